// Round 9
// baseline (187.371 us; speedup 1.0000x reference)
//
#include <hip/hip_runtime.h>
#include <cstdint>

// Problem constants: B=32, C=256, P=32, H=W=56
#define B_    32
#define C_    256
#define P_    32
#define HW_   3136
#define KT    224         // K per round: 14 * 224 = 3136, no tail
#define NR    14          // rounds
#define LDP   232         // padded LDS row stride in shorts (KT + 8)

typedef __attribute__((ext_vector_type(8))) short  short8;   // 8 x bf16 (MFMA A/B frag)
typedef __attribute__((ext_vector_type(4))) float  floatx4;  // MFMA C/D frag

__device__ __forceinline__ unsigned short f2bf(float f) {
    // round-to-nearest-even f32 -> bf16
    union { float f; unsigned u; } v; v.f = f;
    unsigned r = v.u + 0x7fffu + ((v.u >> 16) & 1u);
    return (unsigned short)(r >> 16);
}

// ---------------------------------------------------------------------------
// Kernel 1: wpart[b,p,hw] = bf16( part[b,p,hw] * sigmoid(sum_p' part*w + b) )
// Wave instructions are fully contiguous 1 KB (lane i -> base+16i). ~5 us.
// ---------------------------------------------------------------------------
__global__ __launch_bounds__(64) void wprep_kernel(
    const float* __restrict__ part, const float* __restrict__ conv_w,
    const float* __restrict__ conv_b, unsigned short* __restrict__ wpart)
{
    const int HW4 = HW_ / 4;                          // 784
    int i4 = blockIdx.x * 64 + threadIdx.x;           // over B*HW/4 = 25088
    if (i4 >= B_ * HW4) return;
    int b  = i4 / HW4;
    int hw = (i4 - b * HW4) * 4;

    const float* pb = part + (size_t)b * P_ * HW_ + hw;
    float bias = conv_b[0];
    float4 z = make_float4(bias, bias, bias, bias);
#pragma unroll
    for (int p = 0; p < P_; ++p) {
        float w = conv_w[p];
        float4 v = *(const float4*)(pb + (size_t)p * HW_);
        z.x += v.x * w; z.y += v.y * w; z.z += v.z * w; z.w += v.w * w;
    }
    float4 a;
    a.x = 1.0f / (1.0f + __expf(-z.x));
    a.y = 1.0f / (1.0f + __expf(-z.y));
    a.z = 1.0f / (1.0f + __expf(-z.z));
    a.w = 1.0f / (1.0f + __expf(-z.w));

    unsigned short* ob = wpart + (size_t)b * P_ * HW_ + hw;
#pragma unroll
    for (int p = 0; p < P_; ++p) {
        float4 v = *(const float4*)(pb + (size_t)p * HW_);   // L1/L2-hot reload
        ushort4 o;
        o.x = f2bf(v.x * a.x); o.y = f2bf(v.y * a.y);
        o.z = f2bf(v.z * a.z); o.w = f2bf(v.w * a.w);
        *(ushort4*)(ob + (size_t)p * HW_) = o;
    }
}

// ---------------------------------------------------------------------------
// Kernel 2: page-contiguous double-buffered bf16-MFMA GEMM.
//   feats[b,p,c] = sum_k wpart[b,p,k] * x[b,c,k]
// Grid (8 c-chunks, 32 b) = 256 blocks x 512 thr (8 waves, 1 blk/CU).
// 14 rounds of KT=224. STAGING CONTIGUITY: wave w stages rows w*4..w*4+3;
// each instruction reads ONE row's 896 B contiguously (lane i -> +16B*i,
// lanes 56..63 idle) -- max DRAM page efficiency, unlike R2-R8's 128-256 B
// strided chunks. Double-buffered LDS: round t+1's global loads issue before
// round t's MFMA (a full ~2 us early), ONE barrier per round.
// Compute: wave w (w<7) does k-step w of the round: 4 MFMA.
// Epilogue: LDS reduce over the 8 waves (wave 7 contributes zeros), stores.
// ---------------------------------------------------------------------------
__global__ __launch_bounds__(512) void gemm_tile(
    const float* __restrict__ x,              // [B,C,HW] fp32
    const unsigned short* __restrict__ wpart, // [B,P,HW] bf16
    float* __restrict__ out)                  // [B, P*C]
{
    __shared__ __align__(16) unsigned short Ab[2][P_][LDP];  // 29,696 B
    __shared__ __align__(16) unsigned short Bb[2][32][LDP];  // 29,696 B
    __shared__ float red[8][1024];                           // 32 KB  (total ~92 KB)

    const int ct = blockIdx.x;                // c-chunk 0..7
    const int b  = blockIdx.y;
    const int c0 = ct * 32;

    const int tid  = threadIdx.x;
    const int wv   = tid >> 6;                // 0..7
    const int lane = tid & 63;
    const int qd   = lane >> 4;
    const int r15  = lane & 15;
    const bool sl  = lane < 56;               // 56 lanes * 16B = 896B = KT floats

    const float*          xb = x     + (size_t)b * C_ * HW_;
    const unsigned short* ab = wpart + (size_t)b * P_ * HW_;

    floatx4 acc00 = (floatx4)0.0f, acc01 = (floatx4)0.0f;
    floatx4 acc10 = (floatx4)0.0f, acc11 = (floatx4)0.0f;

    float4  xr[4];    // x staging regs (4 rows)
    ushort4 ar[4];    // wpart staging regs (4 rows)

    // ---- prologue: load round 0, stage into buf 0 ----
#pragma unroll
    for (int j = 0; j < 4; ++j) {
        const int row = wv * 4 + j;
        if (sl) {
            xr[j] = *(const float4*)(xb + (size_t)(c0 + row) * HW_ + lane * 4);
            ar[j] = *(const ushort4*)(ab + (size_t)row * HW_ + lane * 4);
        }
    }
#pragma unroll
    for (int j = 0; j < 4; ++j) {
        const int row = wv * 4 + j;
        if (sl) {
            ushort4 o;
            o.x = f2bf(xr[j].x); o.y = f2bf(xr[j].y);
            o.z = f2bf(xr[j].z); o.w = f2bf(xr[j].w);
            *(ushort4*)&Bb[0][row][lane * 4] = o;
            *(ushort4*)&Ab[0][row][lane * 4] = ar[j];
        }
    }
    __syncthreads();

    for (int t = 0; t < NR; ++t) {
        const int cur = t & 1;
        const int nxt = cur ^ 1;

        // ---- issue round t+1's global loads NOW (~2us before needed) ----
        if (t + 1 < NR) {
            const int kb = (t + 1) * KT;
#pragma unroll
            for (int j = 0; j < 4; ++j) {
                const int row = wv * 4 + j;
                if (sl) {
                    xr[j] = *(const float4*)(xb + (size_t)(c0 + row) * HW_ + kb + lane * 4);
                    ar[j] = *(const ushort4*)(ab + (size_t)row * HW_ + kb + lane * 4);
                }
            }
        }

        // ---- compute on buf cur: wave w takes k-step w (k0 = w*32) ----
        if (wv < 7) {
            const int o = wv * 32 + qd * 8;   // shorts; 16B-aligned
            short8 a0 = *(const short8*)&Ab[cur][r15][o];
            short8 a1 = *(const short8*)&Ab[cur][16 + r15][o];
            short8 b0 = *(const short8*)&Bb[cur][r15][o];
            short8 b1 = *(const short8*)&Bb[cur][16 + r15][o];
            acc00 = __builtin_amdgcn_mfma_f32_16x16x32_bf16(a0, b0, acc00, 0, 0, 0);
            acc01 = __builtin_amdgcn_mfma_f32_16x16x32_bf16(a0, b1, acc01, 0, 0, 0);
            acc10 = __builtin_amdgcn_mfma_f32_16x16x32_bf16(a1, b0, acc10, 0, 0, 0);
            acc11 = __builtin_amdgcn_mfma_f32_16x16x32_bf16(a1, b1, acc11, 0, 0, 0);
        }

        // ---- stage round t+1 into buf nxt ----
        if (t + 1 < NR) {
#pragma unroll
            for (int j = 0; j < 4; ++j) {
                const int row = wv * 4 + j;
                if (sl) {
                    ushort4 o;
                    o.x = f2bf(xr[j].x); o.y = f2bf(xr[j].y);
                    o.z = f2bf(xr[j].z); o.w = f2bf(xr[j].w);
                    *(ushort4*)&Bb[nxt][row][lane * 4] = o;
                    *(ushort4*)&Ab[nxt][row][lane * 4] = ar[j];
                }
            }
        }
        __syncthreads();   // one barrier per round
    }

    // ---- reduction across the 8 waves (wave 7 adds zeros) ----
    // D layout: m = a*16 + qd*4 + rg, n = g*16 + r15 ; local idx = m*32 + n
#pragma unroll
    for (int rg = 0; rg < 4; ++rg) {
        red[wv][(qd * 4 + rg) * 32 + r15]           = acc00[rg];
        red[wv][(qd * 4 + rg) * 32 + 16 + r15]      = acc01[rg];
        red[wv][(16 + qd * 4 + rg) * 32 + r15]      = acc10[rg];
        red[wv][(16 + qd * 4 + rg) * 32 + 16 + r15] = acc11[rg];
    }
    __syncthreads();

#pragma unroll
    for (int h = 0; h < 2; ++h) {
        int idx = h * 512 + tid;              // 0..1023
        float s = 0.0f;
#pragma unroll
        for (int w = 0; w < 8; ++w) s += red[w][idx];
        int p  = idx >> 5;                    // 0..31
        int cl = idx & 31;                    // 0..31
        out[(size_t)b * (P_ * C_) + p * C_ + c0 + cl] = s;
    }
}

extern "C" void kernel_launch(void* const* d_in, const int* in_sizes, int n_in,
                              void* d_out, int out_size, void* d_ws, size_t ws_size,
                              hipStream_t stream) {
    const float* x      = (const float*)d_in[0];
    const float* part   = (const float*)d_in[1];
    const float* conv_w = (const float*)d_in[2];
    const float* conv_b = (const float*)d_in[3];
    unsigned short* wpart = (unsigned short*)d_ws;   // [B,P,HW] bf16 = 6.4 MB

    wprep_kernel<<<dim3((B_ * (HW_ / 4) + 63) / 64), dim3(64), 0, stream>>>(
        part, conv_w, conv_b, wpart);

    gemm_tile<<<dim3(8, B_), dim3(512), 0, stream>>>(
        x, wpart, (float*)d_out);
}